// Round 1
// baseline (73.997 us; speedup 1.0000x reference)
//
#include <hip/hip_runtime.h>
#include <hip/hip_bf16.h>

// Problem constants (Atten_tit): B=16, T=256, K=256, H=512, A=49
#define B_ 16
#define T_ 256
#define K_ 256
#define H_ 512
#define A_ 49

__device__ __forceinline__ float tanh_fast(float x) {
    // tanh(x) = (e^{2x}-1)/(e^{2x}+1); clamp so e stays finite.
    float xc = fminf(fmaxf(x, -15.f), 15.f);
    float e = __expf(2.f * xc);
    return (e - 1.f) * __builtin_amdgcn_rcpf(e + 1.f);
}

// K1: cv[b,k,a] = des[b,k,:]·Wv[a,:]  -> stored transposed cvT (B,A,K)
//     cg[b,t,a] = title[b,t,:]·Wg[a,:] -> stored (B,T,A)
// One wave per row (H=512 -> 8 f32/lane), 64-lane shuffle reduce per a.
__global__ __launch_bounds__(256) void k1_proj(const float* __restrict__ des,
                                               const float* __restrict__ title,
                                               const float* __restrict__ Wv,
                                               const float* __restrict__ Wg,
                                               float* __restrict__ cvT,
                                               float* __restrict__ cg)
{
    int wid  = threadIdx.x >> 6;
    int lane = threadIdx.x & 63;
    int row  = blockIdx.x * 4 + wid;          // 0 .. 8191
    bool isCv = row < B_ * K_;
    const float* W;
    const float* src;
    int r;
    if (isCv) { r = row;            src = des   + (size_t)r * H_; W = Wv; }
    else      { r = row - B_ * K_;  src = title + (size_t)r * H_; W = Wg; }

    const float* p = src + lane * 8;
    float4 x0 = *(const float4*)(p);
    float4 x1 = *(const float4*)(p + 4);

    for (int a = 0; a < A_; ++a) {
        const float* w = W + (size_t)a * H_ + lane * 8;
        float4 w0 = *(const float4*)(w);
        float4 w1 = *(const float4*)(w + 4);
        float s = x0.x*w0.x + x0.y*w0.y + x0.z*w0.z + x0.w*w0.w
                + x1.x*w1.x + x1.y*w1.y + x1.z*w1.z + x1.w*w1.w;
        #pragma unroll
        for (int off = 32; off > 0; off >>= 1) s += __shfl_xor(s, off);
        if (lane == 0) {
            if (isCv) {
                int b = r >> 8, k = r & 255;
                cvT[((size_t)b * A_ + a) * K_ + k] = s;
            } else {
                cg[(size_t)r * A_ + a] = s;
            }
        }
    }
}

// K2: one block per (b,t). Thread k: z = sum_a tanh(cvT[b,a,k]+cg[b,t,a])*Wh[a],
// then block softmax over k -> alpha.
__global__ __launch_bounds__(256) void k2_alpha(const float* __restrict__ cvT,
                                                const float* __restrict__ cg,
                                                const float* __restrict__ Wh,
                                                float* __restrict__ alpha)
{
    __shared__ float sWh[A_];
    __shared__ float sCg[A_];
    __shared__ float sRed[8];

    int bt = blockIdx.x;              // b*T + t
    int b  = bt >> 8;
    int k  = threadIdx.x;

    if (k < A_) {
        sWh[k] = Wh[k];
        sCg[k] = cg[(size_t)bt * A_ + k];
    }
    __syncthreads();

    const float* cvb = cvT + (size_t)b * A_ * K_ + k;
    float z = 0.f;
    #pragma unroll 7
    for (int a = 0; a < A_; ++a) {
        float x = cvb[(size_t)a * K_] + sCg[a];
        z += tanh_fast(x) * sWh[a];
    }

    // block softmax over 256 threads
    int wid = threadIdx.x >> 6, lane = threadIdx.x & 63;
    float m = z;
    #pragma unroll
    for (int off = 32; off > 0; off >>= 1) m = fmaxf(m, __shfl_xor(m, off));
    if (lane == 0) sRed[wid] = m;
    __syncthreads();
    m = fmaxf(fmaxf(sRed[0], sRed[1]), fmaxf(sRed[2], sRed[3]));

    float e = __expf(z - m);
    float s = e;
    #pragma unroll
    for (int off = 32; off > 0; off >>= 1) s += __shfl_xor(s, off);
    if (lane == 0) sRed[4 + wid] = s;
    __syncthreads();
    s = sRed[4] + sRed[5] + sRed[6] + sRed[7];

    alpha[(size_t)bt * K_ + k] = e / s;
}

// K3: c_hat[b] (T x H) = alpha[b] (T x K) * des[b] (K x H), f32 tiled GEMM.
// 64x64 tile, BK=16, 256 threads, 4x4 micro-tile per thread.
__global__ __launch_bounds__(256) void k3_chat(const float* __restrict__ alpha,
                                               const float* __restrict__ des,
                                               float* __restrict__ chat)
{
    __shared__ float As[16][64];   // [kk][t]
    __shared__ float Bs[16][64];   // [kk][h]

    int b  = blockIdx.z;
    int t0 = blockIdx.y * 64;
    int h0 = blockIdx.x * 64;
    int tid = threadIdx.x;
    int tx = tid & 15, ty = tid >> 4;

    float acc[4][4] = {};

    const float* Ab = alpha + (size_t)(b * T_ + t0) * K_;
    const float* Bb = des + (size_t)b * K_ * H_ + h0;

    for (int k0 = 0; k0 < K_; k0 += 16) {
        {   // A tile: 64 t-rows x 16 k, transpose into As[kk][t]
            int row = tid >> 2;
            int kk4 = (tid & 3) * 4;
            float4 v = *(const float4*)(Ab + (size_t)row * K_ + k0 + kk4);
            As[kk4 + 0][row] = v.x;
            As[kk4 + 1][row] = v.y;
            As[kk4 + 2][row] = v.z;
            As[kk4 + 3][row] = v.w;
        }
        {   // B tile: 16 k-rows x 64 h
            int kk = tid >> 4;
            int hj = (tid & 15) * 4;
            *(float4*)(&Bs[kk][hj]) = *(const float4*)(Bb + (size_t)(k0 + kk) * H_ + hj);
        }
        __syncthreads();
        #pragma unroll
        for (int kk = 0; kk < 16; ++kk) {
            float4 av = *(const float4*)(&As[kk][ty * 4]);
            float4 bv = *(const float4*)(&Bs[kk][tx * 4]);
            float a_[4] = {av.x, av.y, av.z, av.w};
            float b_[4] = {bv.x, bv.y, bv.z, bv.w};
            #pragma unroll
            for (int i = 0; i < 4; ++i)
                #pragma unroll
                for (int j = 0; j < 4; ++j)
                    acc[i][j] += a_[i] * b_[j];
        }
        __syncthreads();
    }

    float* C = chat + (size_t)(b * T_ + t0 + ty * 4) * H_ + h0 + tx * 4;
    #pragma unroll
    for (int i = 0; i < 4; ++i) {
        float4 v = make_float4(acc[i][0], acc[i][1], acc[i][2], acc[i][3]);
        *(float4*)(C + (size_t)i * H_) = v;
    }
}

extern "C" void kernel_launch(void* const* d_in, const int* in_sizes, int n_in,
                              void* d_out, int out_size, void* d_ws, size_t ws_size,
                              hipStream_t stream) {
    const float* des   = (const float*)d_in[0];
    const float* title = (const float*)d_in[1];
    const float* Wv    = (const float*)d_in[2];
    const float* Wg    = (const float*)d_in[3];
    const float* Wh    = (const float*)d_in[4];

    float* chat  = (float*)d_out;                           // (B,T,H)
    float* alpha = (float*)d_out + (size_t)B_ * T_ * H_;    // (B,T,K)

    float* cvT = (float*)d_ws;                              // (B,A,K)
    float* cg  = cvT + (size_t)B_ * A_ * K_;                // (B,T,A)

    hipLaunchKernelGGL(k1_proj, dim3((B_ * K_ + B_ * T_) / 4), dim3(256), 0, stream,
                       des, title, Wv, Wg, cvT, cg);
    hipLaunchKernelGGL(k2_alpha, dim3(B_ * T_), dim3(256), 0, stream,
                       cvT, cg, Wh, alpha);
    hipLaunchKernelGGL(k3_chat, dim3(H_ / 64, T_ / 64, B_), dim3(256), 0, stream,
                       alpha, des, chat);
}

// Round 2
// 68.367 us; speedup vs baseline: 1.0824x; 1.0824x over previous
//
#include <hip/hip_runtime.h>
#include <hip/hip_bf16.h>

// Problem constants (Atten_tit): B=16, T=256, K=256, H=512, A=49
#define B_ 16
#define T_ 256
#define K_ 256
#define H_ 512
#define A_ 49

typedef __attribute__((ext_vector_type(8))) short short8;   // bf16x8 (4 VGPR)
typedef __attribute__((ext_vector_type(4))) float f32x4;

__device__ __forceinline__ ushort f2bf(float f) {
    uint u = __builtin_bit_cast(uint, f);
    u += 0x7FFF + ((u >> 16) & 1);   // RNE
    return (ushort)(u >> 16);
}

__device__ __forceinline__ float tanh_fast(float x) {
    float xc = fminf(fmaxf(x, -15.f), 15.f);
    float e = __expf(2.f * xc);
    return (e - 1.f) * __builtin_amdgcn_rcpf(e + 1.f);
}

// ---------------------------------------------------------------------------
// K0: transpose des (B,K,H) f32 -> desT (B,H,K) bf16.  32x32 LDS tiles.
__global__ __launch_bounds__(256) void k0_transT(const float* __restrict__ des,
                                                 ushort* __restrict__ desT)
{
    __shared__ float Tls[32][33];
    int b  = blockIdx.z;
    int k0 = blockIdx.y * 32;
    int h0 = blockIdx.x * 32;
    int tid = threadIdx.x;

    {   // load 32(k) x 32(h), coalesced over h
        int kk  = tid >> 3;
        int c4  = (tid & 7) * 4;
        float4 v = *(const float4*)(des + ((size_t)(b * K_ + k0 + kk) * H_) + h0 + c4);
        Tls[kk][c4 + 0] = v.x; Tls[kk][c4 + 1] = v.y;
        Tls[kk][c4 + 2] = v.z; Tls[kk][c4 + 3] = v.w;
    }
    __syncthreads();
    {   // store 32(h) x 32(k), coalesced over k, bf16
        int hh  = tid >> 3;
        int c4  = (tid & 7) * 4;
        ushort4 o;
        o.x = f2bf(Tls[c4 + 0][hh]);
        o.y = f2bf(Tls[c4 + 1][hh]);
        o.z = f2bf(Tls[c4 + 2][hh]);
        o.w = f2bf(Tls[c4 + 3][hh]);
        *(ushort4*)(desT + ((size_t)(b * H_ + h0 + hh) * K_) + k0 + c4) = o;
    }
}

// ---------------------------------------------------------------------------
// K1: tiled f32 GEMM  C(8192 x 64) = X(8192 x 512) * W^T(512 x 64), 49 cols valid.
// Rows 0..4095 = des (-> cvT transposed (B,A,K)); rows 4096..8191 = title (-> cg (B*T,A)).
// M-tile 32, N-tile 64, K-tile 16, 256 threads, micro 2x4.
__global__ __launch_bounds__(256) void k1_gemm(const float* __restrict__ des,
                                               const float* __restrict__ title,
                                               const float* __restrict__ Wv,
                                               const float* __restrict__ Wg,
                                               float* __restrict__ cvT,
                                               float* __restrict__ cg)
{
    __shared__ float Xs[16][34];   // [kk][row]
    __shared__ float Ws[16][68];   // [kk][a]

    bool isCv = blockIdx.x < 128;
    int r0 = (isCv ? blockIdx.x : blockIdx.x - 128) * 32;
    const float* X = (isCv ? des : title) + (size_t)r0 * H_;
    const float* W = isCv ? Wv : Wg;

    int tid = threadIdx.x;
    int tx = tid & 15, ty = tid >> 4;      // tx: a-group, ty: row-group
    float acc[2][4] = {};

    // load-index precompute
    int lrow = tid >> 3, lk2 = (tid & 7) * 2;     // X tile load
    int wa = tid >> 2, wk4 = (tid & 3) * 4;       // W tile load

    for (int k0 = 0; k0 < H_; k0 += 16) {
        {   float2 v = *(const float2*)(X + (size_t)lrow * H_ + k0 + lk2);
            Xs[lk2][lrow] = v.x; Xs[lk2 + 1][lrow] = v.y;
        }
        {   float4 v = make_float4(0.f, 0.f, 0.f, 0.f);
            if (wa < A_) v = *(const float4*)(W + (size_t)wa * H_ + k0 + wk4);
            Ws[wk4 + 0][wa] = v.x; Ws[wk4 + 1][wa] = v.y;
            Ws[wk4 + 2][wa] = v.z; Ws[wk4 + 3][wa] = v.w;
        }
        __syncthreads();
        #pragma unroll
        for (int kk = 0; kk < 16; ++kk) {
            float2 av = *(const float2*)(&Xs[kk][ty * 2]);
            float4 bv = *(const float4*)(&Ws[kk][tx * 4]);
            float a_[2] = {av.x, av.y};
            float b_[4] = {bv.x, bv.y, bv.z, bv.w};
            #pragma unroll
            for (int i = 0; i < 2; ++i)
                #pragma unroll
                for (int j = 0; j < 4; ++j)
                    acc[i][j] += a_[i] * b_[j];
        }
        __syncthreads();
    }

    if (isCv) {
        int b = r0 >> 8, kbase = r0 & 255;
        #pragma unroll
        for (int j = 0; j < 4; ++j) {
            int a = tx * 4 + j;
            if (a < A_) {
                #pragma unroll
                for (int i = 0; i < 2; ++i)
                    cvT[((size_t)(b * A_ + a)) * K_ + kbase + ty * 2 + i] = acc[i][j];
            }
        }
    } else {
        #pragma unroll
        for (int i = 0; i < 2; ++i) {
            int r = r0 + ty * 2 + i;
            #pragma unroll
            for (int j = 0; j < 4; ++j) {
                int a = tx * 4 + j;
                if (a < A_) cg[(size_t)r * A_ + a] = acc[i][j];
            }
        }
    }
}

// ---------------------------------------------------------------------------
// K2: one block per (b,t). Thread k: z = sum_a tanh(cvT[b,a,k]+cg[b,t,a])*Wh[a],
// block softmax -> alpha (f32 out) + alpha_bf16 (ws).
__global__ __launch_bounds__(256) void k2_alpha(const float* __restrict__ cvT,
                                                const float* __restrict__ cg,
                                                const float* __restrict__ Wh,
                                                float* __restrict__ alpha,
                                                ushort* __restrict__ alphaBf)
{
    __shared__ float sWh[A_];
    __shared__ float sCg[A_];
    __shared__ float sRed[8];

    int bt = blockIdx.x;
    int b  = bt >> 8;
    int k  = threadIdx.x;

    if (k < A_) {
        sWh[k] = Wh[k];
        sCg[k] = cg[(size_t)bt * A_ + k];
    }
    __syncthreads();

    const float* cvb = cvT + (size_t)b * A_ * K_ + k;
    float z = 0.f;
    #pragma unroll 7
    for (int a = 0; a < A_; ++a) {
        float x = cvb[(size_t)a * K_] + sCg[a];
        z += tanh_fast(x) * sWh[a];
    }

    int wid = threadIdx.x >> 6, lane = threadIdx.x & 63;
    float m = z;
    #pragma unroll
    for (int off = 32; off > 0; off >>= 1) m = fmaxf(m, __shfl_xor(m, off));
    if (lane == 0) sRed[wid] = m;
    __syncthreads();
    m = fmaxf(fmaxf(sRed[0], sRed[1]), fmaxf(sRed[2], sRed[3]));

    float e = __expf(z - m);
    float s = e;
    #pragma unroll
    for (int off = 32; off > 0; off >>= 1) s += __shfl_xor(s, off);
    if (lane == 0) sRed[4 + wid] = s;
    __syncthreads();
    s = sRed[4] + sRed[5] + sRed[6] + sRed[7];

    float v = e * __builtin_amdgcn_rcpf(s);
    // improve rcp with one Newton step for accuracy
    float rs = __builtin_amdgcn_rcpf(s);
    rs = rs * (2.f - s * rs);
    v = e * rs;
    alpha[(size_t)bt * K_ + k] = v;
    alphaBf[(size_t)bt * K_ + k] = f2bf(v);
}

// ---------------------------------------------------------------------------
// K3: c_hat[b] (T x H) = alpha[b] (T x K) * des[b] (K x H) via bf16 MFMA.
// A = alphaBf (B,T,K) row-major; B-op = desT (B,H,K) k-major. 64x64 block tile,
// 4 waves each 32x32 (2x2 fragments of 16x16x32). Fragments straight from L2.
__global__ __launch_bounds__(256) void k3_mfma(const ushort* __restrict__ aBf,
                                               const ushort* __restrict__ desT,
                                               float* __restrict__ chat)
{
    int b  = blockIdx.z;
    int t0 = blockIdx.y * 64;
    int h0 = blockIdx.x * 64;
    int wid  = threadIdx.x >> 6;
    int lane = threadIdx.x & 63;
    int wt = (wid >> 1) * 32;
    int wh = (wid & 1) * 32;
    int lr = lane & 15, lc = lane >> 4;

    const ushort* Ab = aBf  + ((size_t)(b * T_ + t0 + wt) + lr) * K_ + lc * 8;
    const ushort* Bb = desT + ((size_t)(b * H_ + h0 + wh) + lr) * K_ + lc * 8;

    f32x4 acc[2][2] = {};

    #pragma unroll
    for (int k0 = 0; k0 < K_; k0 += 32) {
        short8 af[2], bfr[2];
        #pragma unroll
        for (int i = 0; i < 2; ++i)
            af[i] = *(const short8*)(Ab + (size_t)16 * i * K_ + k0);
        #pragma unroll
        for (int j = 0; j < 2; ++j)
            bfr[j] = *(const short8*)(Bb + (size_t)16 * j * K_ + k0);
        #pragma unroll
        for (int i = 0; i < 2; ++i)
            #pragma unroll
            for (int j = 0; j < 2; ++j)
                acc[i][j] = __builtin_amdgcn_mfma_f32_16x16x32_bf16(af[i], bfr[j], acc[i][j], 0, 0, 0);
    }

    #pragma unroll
    for (int i = 0; i < 2; ++i) {
        #pragma unroll
        for (int j = 0; j < 2; ++j) {
            #pragma unroll
            for (int r = 0; r < 4; ++r) {
                int row = t0 + wt + 16 * i + lc * 4 + r;
                int col = h0 + wh + 16 * j + lr;
                chat[((size_t)(b * T_ + row)) * H_ + col] = acc[i][j][r];
            }
        }
    }
}

// ---------------------------------------------------------------------------
extern "C" void kernel_launch(void* const* d_in, const int* in_sizes, int n_in,
                              void* d_out, int out_size, void* d_ws, size_t ws_size,
                              hipStream_t stream) {
    const float* des   = (const float*)d_in[0];
    const float* title = (const float*)d_in[1];
    const float* Wv    = (const float*)d_in[2];
    const float* Wg    = (const float*)d_in[3];
    const float* Wh    = (const float*)d_in[4];

    float* chat  = (float*)d_out;                            // (B,T,H)
    float* alpha = (float*)d_out + (size_t)B_ * T_ * H_;     // (B,T,K)

    char* ws = (char*)d_ws;
    float*  cvT     = (float*)ws;                                   // (B,A,K) f32
    float*  cg      = cvT + (size_t)B_ * A_ * K_;                   // (B*T,A) f32
    ushort* desT    = (ushort*)(ws + 2 * (size_t)B_ * A_ * K_ * 4 + (size_t)B_ * (T_ - A_) * 0 + 0);
    // recompute cleanly:
    size_t off = (size_t)B_ * A_ * K_ * 4 + (size_t)B_ * T_ * A_ * 4;
    off = (off + 15) & ~(size_t)15;
    desT = (ushort*)(ws + off);                                     // (B,H,K) bf16
    off += (size_t)B_ * H_ * K_ * 2;
    off = (off + 15) & ~(size_t)15;
    ushort* alphaBf = (ushort*)(ws + off);                          // (B,T,K) bf16

    hipLaunchKernelGGL(k0_transT, dim3(H_ / 32, K_ / 32, B_), dim3(256), 0, stream,
                       des, desT);
    hipLaunchKernelGGL(k1_gemm, dim3(256), dim3(256), 0, stream,
                       des, title, Wv, Wg, cvT, cg);
    hipLaunchKernelGGL(k2_alpha, dim3(B_ * T_), dim3(256), 0, stream,
                       cvT, cg, Wh, alpha, alphaBf);
    hipLaunchKernelGGL(k3_mfma, dim3(H_ / 64, T_ / 64, B_), dim3(256), 0, stream,
                       alphaBf, desT, chat);
}